// Round 5
// baseline (127.598 us; speedup 1.0000x reference)
//
#include <hip/hip_runtime.h>
#include <hip/hip_bf16.h>
#include <math.h>

// Problem: B=2, N=8192, M=8192, C=3, k=20; MLP 20->256->128->1 with BN+ReLU, sigmoid.
// Pipeline (3 launches):
//   k_prep : y -> 4 SoA planes (y0, y1, y2, -|y|^2) per batch + W2 transpose.
//   k_knn  : per-row top-20 LARGEST pd = 2x.y - xx - yy. One wave per row.
//            4-op distance, per-lane sorted top-4 (3 med3 + 1 max),
//            register-double-buffered plane loads. 32 iters x 4 cand = 8192. (R4
//            bug: ran 16 iters = half the candidates.) 20-round cross-lane
//            max-merge; exactness guard (lane pops all 4 slots -> exact redo).
//   k_mlp  : fused MLP, 32 rows/block (101 KB LDS). feat+h1 in LDS; GEMM vs
//            W2 in two 64-out halves; bn2+relu+W3 dot in-wave; sigmoid.

#define M_CAND 8192
#define NROWS 16384
#define KSEL 20
#define MPL 4            // per-lane list length (main path)

__device__ __forceinline__ float med3f(float a, float b, float c) {
    return __builtin_amdgcn_fmed3f(a, b, c);
}

// ---------- kernel: prep (y planes + W2 transpose) ----------
__global__ __launch_bounds__(256) void k_prep(const float* __restrict__ y,
                                              const float* __restrict__ w2,
                                              float* __restrict__ ys,
                                              float* __restrict__ w2t) {
    int idx = blockIdx.x * 256 + threadIdx.x;     // 49152 total
    if (idx < NROWS) {                            // 16384 candidate points
        int b = idx >> 13, m = idx & 8191;
        const float* p = y + (size_t)idx * 3;
        float y0 = p[0], y1 = p[1], y2 = p[2];
        float* base = ys + (size_t)b * 4 * M_CAND + m;
        base[0]          = y0;
        base[M_CAND]     = y1;
        base[2 * M_CAND] = y2;
        base[3 * M_CAND] = -(y0 * y0 + y1 * y1 + y2 * y2);
    } else {
        int j = idx - NROWS;                      // 32768 W2 elements
        int o = j >> 8, kk = j & 255;
        w2t[kk * 128 + o] = w2[j];
    }
}

// ---------- kernel: kNN top-20 by pd (one wave per row) ----------
__global__ __launch_bounds__(256, 4) void k_knn(const float* __restrict__ x,
                                                const float* __restrict__ ys,
                                                float* __restrict__ dfeat) {
    __shared__ float sm[4][64 * 21];              // per-wave region, stride 5 / 21
    const int wid  = threadIdx.x >> 6;
    const int lane = threadIdx.x & 63;
    const int row  = blockIdx.x * 4 + wid;        // grid 4096 -> rows 0..16383
    const int b    = row >> 13;
    const float x0 = x[row * 3 + 0];
    const float x1 = x[row * 3 + 1];
    const float x2 = x[row * 3 + 2];
    const float tx0 = 2.0f * x0, tx1 = 2.0f * x1, tx2 = 2.0f * x2;
    const float xxn = -(x0 * x0 + x1 * x1 + x2 * x2);
    const float4* q0 = (const float4*)(ys + (size_t)(b * 4 + 0) * M_CAND) + lane;
    const float4* q1 = (const float4*)(ys + (size_t)(b * 4 + 1) * M_CAND) + lane;
    const float4* q2 = (const float4*)(ys + (size_t)(b * 4 + 2) * M_CAND) + lane;
    const float4* q3 = (const float4*)(ys + (size_t)(b * 4 + 3) * M_CAND) + lane;

    // descending per-lane top-4 of pd (largest pd = nearest)
    float bl[MPL];
#pragma unroll
    for (int j = 0; j < MPL; ++j) bl[j] = -3.0e38f;

    // register double-buffer: prefetch iter t+1's planes while computing t.
    // Each plane is 2048 float4; 32 iters x 64 lanes x 4 cand = 8192 candidates.
    float4 c0 = q0[0], c1 = q1[0], c2 = q2[0], c3 = q3[0];
#pragma unroll 1
    for (int t = 0; t < 32; ++t) {
        const int nt = ((t + 1) & 31) * 64;
        float4 n0 = q0[nt], n1 = q1[nt], n2 = q2[nt], n3 = q3[nt];
        const float* e0 = (const float*)&c0;
        const float* e1 = (const float*)&c1;
        const float* e2 = (const float*)&c2;
        const float* e3 = (const float*)&c3;
#pragma unroll
        for (int j = 0; j < 4; ++j) {
            float v = fmaf(tx0, e0[j], fmaf(tx1, e1[j], fmaf(tx2, e2[j], xxn))) + e3[j];
            // branchless sorted insert (reads pre-candidate values: independent)
            bl[3] = med3f(v, bl[2], bl[3]);
            bl[2] = med3f(v, bl[1], bl[2]);
            bl[1] = med3f(v, bl[0], bl[1]);
            bl[0] = fmaxf(bl[0], v);
        }
        c0 = n0; c1 = n1; c2 = n2; c3 = n3;
    }

    // cross-lane merge: 20 rounds of wave-max over per-lane sorted heads
    float* myp = sm[wid] + lane * (MPL + 1);      // stride 5: conflict-free
#pragma unroll
    for (int j = 0; j < MPL; ++j) myp[j] = bl[j];
    myp[MPL] = -3.0e38f;                          // pad slot
    asm volatile("s_waitcnt lgkmcnt(0)" ::: "memory");

    int ptr = 0;
    float sel = 0.0f;
    for (int r = 0; r < KSEL; ++r) {
        float head = myp[ptr];
        float mx = head;
#pragma unroll
        for (int off = 32; off >= 1; off >>= 1) mx = fmaxf(mx, __shfl_xor(mx, off, 64));
        unsigned long long ball = __ballot(head == mx);
        int winner = (int)__ffsll(ball) - 1;      // first lane holding max (tie-safe)
        ptr += (lane == winner) ? 1 : 0;
        if (lane == r) sel = mx;
    }

    // exactness guard: lane drained all 4 slots -> row may be wrong -> exact redo
    bool need_exact = (__ballot(ptr >= MPL) != 0ULL);
    if (need_exact) {
        float a[KSEL];
#pragma unroll
        for (int j = 0; j < KSEL; ++j) a[j] = -3.0e38f;
        for (int t = 0; t < 32; ++t) {
            float4 d0 = q0[t * 64], d1 = q1[t * 64], d2 = q2[t * 64], d3 = q3[t * 64];
            const float* e0 = (const float*)&d0;
            const float* e1 = (const float*)&d1;
            const float* e2 = (const float*)&d2;
            const float* e3 = (const float*)&d3;
#pragma unroll
            for (int j = 0; j < 4; ++j) {
                float v = fmaf(tx0, e0[j], fmaf(tx1, e1[j], fmaf(tx2, e2[j], xxn))) + e3[j];
#pragma unroll
                for (int jj = KSEL - 1; jj >= 1; --jj) a[jj] = med3f(v, a[jj - 1], a[jj]);
                a[0] = fmaxf(a[0], v);
            }
        }
        float* mq = sm[wid] + lane * (KSEL + 1);  // stride 21
#pragma unroll
        for (int j = 0; j < KSEL; ++j) mq[j] = a[j];
        mq[KSEL] = -3.0e38f;
        asm volatile("s_waitcnt lgkmcnt(0)" ::: "memory");
        int ptr2 = 0;
        for (int r = 0; r < KSEL; ++r) {
            float head = mq[ptr2];
            float mx = head;
#pragma unroll
            for (int off = 32; off >= 1; off >>= 1) mx = fmaxf(mx, __shfl_xor(mx, off, 64));
            unsigned long long ball = __ballot(head == mx);
            int winner = (int)__ffsll(ball) - 1;
            ptr2 += (lane == winner) ? 1 : 0;
            if (lane == r) sel = mx;
        }
    }

    if (lane < KSEL) dfeat[row * KSEL + lane] = sel;
}

// ---------- kernel: fused MLP (bn1/relu -> GEMM2 -> bn2/relu -> W3 -> sigmoid) ----------
__global__ __launch_bounds__(256) void k_mlp(const float* __restrict__ dfeat,
                                             const float* __restrict__ W1,
                                             const float* __restrict__ g1,
                                             const float* __restrict__ be1,
                                             const float* __restrict__ mu1,
                                             const float* __restrict__ va1,
                                             const float* __restrict__ W2T,
                                             const float* __restrict__ g2,
                                             const float* __restrict__ be2,
                                             const float* __restrict__ mu2,
                                             const float* __restrict__ va2,
                                             const float* __restrict__ W3,
                                             float* __restrict__ out) {
    __shared__ float h1l[32 * 260];               // 33,280 B (stride 260: conflict-free)
    __shared__ float w2l[256 * 64];               // 65,536 B [k][oo] k-major
    __shared__ float featl[640];                  // 2,560 B  (total ~101 KB)
    const int t = threadIdx.x;
    const int rowbase = blockIdx.x * 32;          // grid 512 -> all 16384 rows

    // cooperative stage: feat rows (32 x 20 floats = 160 float4)
    for (int i = t; i < 160; i += 256)
        ((float4*)featl)[i] = *(const float4*)(dfeat + (size_t)rowbase * KSEL + i * 4);
    // stage W2 half 0 ([256][64] k-major)
    {
        const int oo4 = (t & 15) * 4;
        const int k0  = t >> 4;
        for (int i = 0; i < 16; ++i) {
            int k = k0 + 16 * i;
            *(float4*)(&w2l[k * 64 + oo4]) = *(const float4*)(W2T + k * 128 + oo4);
        }
    }

    // phase-1 per-thread weights (o = t)
    float w[KSEL];
#pragma unroll
    for (int j = 0; j < KSEL; j += 4) {
        float4 q = *(const float4*)(W1 + t * KSEL + j);
        w[j] = q.x; w[j + 1] = q.y; w[j + 2] = q.z; w[j + 3] = q.w;
    }
    const float s1  = g1[t] * rsqrtf(va1[t] + 1e-5f);
    const float bc1 = be1[t] - mu1[t] * s1;

    __syncthreads();                              // featl + w2l half0 ready

    // phase 1: h1[r][o] = relu(bn1(W1 . feat)), o = t, r = 0..31
    for (int r = 0; r < 32; ++r) {
        const float* fr = featl + r * KSEL;       // broadcast reads
        float acc0 = 0.f, acc1 = 0.f;
#pragma unroll
        for (int j = 0; j < KSEL; j += 2) {
            acc0 = fmaf(w[j], fr[j], acc0);
            acc1 = fmaf(w[j + 1], fr[j + 1], acc1);
        }
        h1l[r * 260 + t] = fmaxf(0.f, fmaf(s1, acc0 + acc1, bc1));
    }
    __syncthreads();                              // h1l ready

    // phase 2: GEMM 32 rows x 128 outs in two 64-out halves
    const int og = t & 15;                        // 4 outs per half: og*4 + i
    const int rq = t >> 4;                        // 2 rows: rq*2 + rr
    float cacc[2] = {0.f, 0.f};

    for (int half = 0; half < 2; ++half) {
        if (half == 1) {
            __syncthreads();                      // half-0 reads done
            const int oo4 = (t & 15) * 4;
            const int k0  = t >> 4;
            for (int i = 0; i < 16; ++i) {
                int k = k0 + 16 * i;
                *(float4*)(&w2l[k * 64 + oo4]) = *(const float4*)(W2T + k * 128 + 64 + oo4);
            }
            __syncthreads();                      // half-1 staged
        }

        float acc[2][4];
#pragma unroll
        for (int r = 0; r < 2; ++r)
#pragma unroll
            for (int i = 0; i < 4; ++i) acc[r][i] = 0.f;

        for (int kq = 0; kq < 64; ++kq) {
            const int k = kq * 4;
            float4 hq[2];
#pragma unroll
            for (int rr = 0; rr < 2; ++rr)
                hq[rr] = *(const float4*)(&h1l[(rq * 2 + rr) * 260 + k]);
            float4 wq[4];
#pragma unroll
            for (int kk = 0; kk < 4; ++kk)
                wq[kk] = *(const float4*)(&w2l[(k + kk) * 64 + og * 4]);
#pragma unroll
            for (int r = 0; r < 2; ++r) {
                const float* hh = (const float*)&hq[r];
#pragma unroll
                for (int kk = 0; kk < 4; ++kk) {
                    const float* ww = (const float*)&wq[kk];
                    const float hval = hh[kk];
#pragma unroll
                    for (int i = 0; i < 4; ++i)
                        acc[r][i] = fmaf(hval, ww[i], acc[r][i]);
                }
            }
        }

        // epilogue: bn2 + relu + W3 weighting, reduce over og group (16 lanes)
        float s2v[4], b2v[4], w3v[4];
#pragma unroll
        for (int i = 0; i < 4; ++i) {
            const int o = half * 64 + og * 4 + i;
            const float sv = g2[o] * rsqrtf(va2[o] + 1e-5f);
            s2v[i] = sv;
            b2v[i] = be2[o] - mu2[o] * sv;
            w3v[i] = W3[o];
        }
#pragma unroll
        for (int r = 0; r < 2; ++r) {
            float c = 0.f;
#pragma unroll
            for (int i = 0; i < 4; ++i) {
                float h2 = fmaxf(0.f, fmaf(s2v[i], acc[r][i], b2v[i]));
                c = fmaf(w3v[i], h2, c);
            }
#pragma unroll
            for (int off = 8; off >= 1; off >>= 1) c += __shfl_xor(c, off, 64);
            cacc[r] += c;
        }
    }

    if (og == 0) {
#pragma unroll
        for (int r = 0; r < 2; ++r) {
            float z = cacc[r];
            out[rowbase + rq * 2 + r] = 1.0f / (1.0f + expf(-z));
        }
    }
}

extern "C" void kernel_launch(void* const* d_in, const int* in_sizes, int n_in,
                              void* d_out, int out_size, void* d_ws, size_t ws_size,
                              hipStream_t stream) {
    const float* x   = (const float*)d_in[0];
    const float* y   = (const float*)d_in[1];
    const float* W1  = (const float*)d_in[2];
    const float* g1  = (const float*)d_in[3];
    const float* be1 = (const float*)d_in[4];
    const float* mu1 = (const float*)d_in[5];
    const float* va1 = (const float*)d_in[6];
    const float* W2  = (const float*)d_in[7];
    const float* g2  = (const float*)d_in[8];
    const float* be2 = (const float*)d_in[9];
    const float* mu2 = (const float*)d_in[10];
    const float* va2 = (const float*)d_in[11];
    const float* W3  = (const float*)d_in[12];
    float* out = (float*)d_out;

    char* ws = (char*)d_ws;
    float* ys    = (float*)(ws);                                    // 262,144 B
    float* dfeat = (float*)(ws + 262144);                           // 1,310,720 B
    float* w2t   = (float*)(ws + 262144 + 1310720);                 // 131,072 B

    k_prep<<<192, 256, 0, stream>>>(y, W2, ys, w2t);
    k_knn <<<4096, 256, 0, stream>>>(x, ys, dfeat);
    k_mlp <<<512, 256, 0, stream>>>(dfeat, W1, g1, be1, mu1, va1,
                                    w2t, g2, be2, mu2, va2, W3, out);
}